// Round 1
// baseline (539.682 us; speedup 1.0000x reference)
//
#include <hip/hip_runtime.h>
#include <hip/hip_bf16.h>

// LCA sparsifier: 10 iterations of v = 0.9v + 0.1u - 0.1*(a@G); a = soft(v, lam)
// Fused persistent-row design: each block owns 64 rows across all 10 iterations.
// - acc registers double as v-state: C_init = -9v - u, after GEMM C = P-9v-u,
//   v_new = -0.1*C, next C_init = 0.9*C - u.
// - a round-trips through LDS as bf16 (MFMA A-operand layout, padded stride 520).
// - G pre-swizzled to bf16 B-fragment order (prep kernel) -> coalesced 16B L2 loads.

typedef __attribute__((ext_vector_type(8))) short bf16x8;
typedef __attribute__((ext_vector_type(16))) float f32x16;

#define ETA 0.1f

__device__ __forceinline__ unsigned short f2bf(float f) {
  union { float f; unsigned u; } x; x.f = f;
  unsigned r = x.u + 0x7fffu + ((x.u >> 16) & 1u);  // round-to-nearest-even
  return (unsigned short)(r >> 16);
}

// ---- prep: G = 0.5(Graw + Graw^T), zero diag, bf16, swizzled into
// mfma_f32_32x32x16_bf16 B-fragment order: B[k][n], lane = (n&31) + 32*((k>>3)&1),
// j = k&7, frag index = (kk*16 + ct)*64 + lane  with kk=k>>4, ct=n>>5.
__global__ void prep_G(const float* __restrict__ Graw, unsigned short* __restrict__ Gb) {
  int idx = blockIdx.x * blockDim.x + threadIdx.x;  // 512*512 elements
  int k = idx >> 9, n = idx & 511;
  float g = 0.5f * (Graw[k * 512 + n] + Graw[n * 512 + k]);
  if (k == n) g = 0.f;
  int kk = k >> 4, ct = n >> 5;
  int lane = (n & 31) + (((k >> 3) & 1) << 5);
  int j = k & 7;
  Gb[((((kk * 16 + ct) * 64) + lane) << 3) + j] = f2bf(g);
}

__global__ __launch_bounds__(512, 2) void lca_kernel(
    const float* __restrict__ u_g, const unsigned short* __restrict__ Gb,
    const float* __restrict__ log_lam, float* __restrict__ out) {
  // a-buffer: 64 rows x 512 cols bf16, row stride 520 (1040B = 16*65 -> the
  // 8-lane b128 phases of an A-fragment read cover all 8 bank groups).
  __shared__ unsigned short sA[64 * 520];

  const int tid = threadIdx.x;
  const int lane = tid & 63;
  const int wave = tid >> 6;           // 0..7, owns cols [wave*64, wave*64+64)
  const int R0 = blockIdx.x * 64;      // block's global row base
  const int cl = lane & 31;            // col within 32-tile / A-row within tile
  const int rquad = (lane >> 5) * 4;   // C-layout row contribution of lane-half
  const int C0 = wave * 64;

  const float lam = expf(log_lam[0]);

  f32x16 acc[2][2];  // [row-tile][col-tile], C layout: col=lane&31,
                     // row=(reg&3)+8*(reg>>2)+4*(lane>>5)
  f32x16 uu[2][2];

  // ---- load u in C layout; init acc = -u  (t=0: v=0, P=0 -> C = -9v-u = -u)
  #pragma unroll
  for (int rt = 0; rt < 2; ++rt) {
    #pragma unroll
    for (int ctl = 0; ctl < 2; ++ctl) {
      const float* base = u_g + (R0 + rt * 32 + rquad) * 512 + C0 + ctl * 32 + cl;
      f32x16 t;
      #pragma unroll
      for (int reg = 0; reg < 16; ++reg) {
        const int rofs = (reg & 3) + 8 * (reg >> 2);
        t[reg] = base[rofs * 512];
      }
      uu[rt][ctl] = t;
      acc[rt][ctl] = -t;
    }
  }

  // epilogue: a = soft(-ETA*acc) -> LDS (bf16, A layout = plain [row][k] padded);
  // then re-init acc for next iteration: acc = 0.9*acc - u
  auto epilogue = [&]() {
    #pragma unroll
    for (int rt = 0; rt < 2; ++rt) {
      #pragma unroll
      for (int ctl = 0; ctl < 2; ++ctl) {
        unsigned short* sa = &sA[(rt * 32 + rquad) * 520 + C0 + ctl * 32 + cl];
        #pragma unroll
        for (int reg = 0; reg < 16; ++reg) {
          const int rofs = (reg & 3) + 8 * (reg >> 2);
          float v = -ETA * acc[rt][ctl][reg];
          float av = copysignf(fmaxf(fabsf(v) - lam, 0.f), v);
          sa[rofs * 520] = f2bf(av);
        }
        acc[rt][ctl] = 0.9f * acc[rt][ctl] - uu[rt][ctl];
      }
    }
  };

  // t = 0: P = 0, GEMM skipped (a_0 = 0). Writes a_1 into LDS.
  epilogue();
  __syncthreads();

  // A-fragment base: A[m][k], m = lane&31 (local row), k = kk*16 + (lane>>5)*8 + j
  const unsigned short* paRow = sA + cl * 520 + ((lane >> 5) << 3);
  const bf16x8* gb = (const bf16x8*)Gb;
  const int bbase = wave * 2 * 64 + lane;  // + kk*1024 (+64 for second col-tile)

  #pragma unroll 1
  for (int t = 1; t < 10; ++t) {
    #pragma unroll 4
    for (int kk = 0; kk < 32; ++kk) {
      bf16x8 a0 = *(const bf16x8*)(paRow + kk * 16);
      bf16x8 a1 = *(const bf16x8*)(paRow + 32 * 520 + kk * 16);
      bf16x8 b0 = gb[bbase + kk * 1024];
      bf16x8 b1 = gb[bbase + kk * 1024 + 64];
      acc[0][0] = __builtin_amdgcn_mfma_f32_32x32x16_bf16(a0, b0, acc[0][0], 0, 0, 0);
      acc[0][1] = __builtin_amdgcn_mfma_f32_32x32x16_bf16(a0, b1, acc[0][1], 0, 0, 0);
      acc[1][0] = __builtin_amdgcn_mfma_f32_32x32x16_bf16(a1, b0, acc[1][0], 0, 0, 0);
      acc[1][1] = __builtin_amdgcn_mfma_f32_32x32x16_bf16(a1, b1, acc[1][1], 0, 0, 0);
    }
    __syncthreads();  // all A-reads of this iteration done
    if (t < 9) {
      epilogue();     // write a_{t+1}, update acc
      __syncthreads();
    }
  }

  // ---- final output: a_10 = soft(-ETA * acc)
  #pragma unroll
  for (int rt = 0; rt < 2; ++rt) {
    #pragma unroll
    for (int ctl = 0; ctl < 2; ++ctl) {
      float* ob = out + (R0 + rt * 32 + rquad) * 512 + C0 + ctl * 32 + cl;
      #pragma unroll
      for (int reg = 0; reg < 16; ++reg) {
        const int rofs = (reg & 3) + 8 * (reg >> 2);
        float v = -ETA * acc[rt][ctl][reg];
        ob[rofs * 512] = copysignf(fmaxf(fabsf(v) - lam, 0.f), v);
      }
    }
  }
}

extern "C" void kernel_launch(void* const* d_in, const int* in_sizes, int n_in,
                              void* d_out, int out_size, void* d_ws, size_t ws_size,
                              hipStream_t stream) {
  const float* u = (const float*)d_in[0];
  const float* Graw = (const float*)d_in[1];
  const float* log_lam = (const float*)d_in[2];
  float* out = (float*)d_out;
  unsigned short* Gb = (unsigned short*)d_ws;  // 512*512*2 = 512 KB scratch

  prep_G<<<dim3(1024), dim3(256), 0, stream>>>(Graw, Gb);
  lca_kernel<<<dim3(1024), dim3(512), 0, stream>>>(u, Gb, log_lam, out);
}